// Round 10
// baseline (233.270 us; speedup 1.0000x reference)
//
#include <hip/hip_runtime.h>
#include <hip/hip_cooperative_groups.h>
#include <stdint.h>

namespace cg = cooperative_groups;

typedef __bf16 bf16x8 __attribute__((ext_vector_type(8)));
typedef short  short4v __attribute__((ext_vector_type(4)));   // 4 x bf16 bits
typedef float  floatx4 __attribute__((ext_vector_type(4)));
typedef uint32_t u32x4 __attribute__((ext_vector_type(4)));

#define DI __device__ __forceinline__

DI uint16_t f2bf(float f) {
    union { float f; uint32_t i; } v; v.f = f;
    uint32_t u = v.i;
    return (uint16_t)((u + 0x7FFFu + ((u >> 16) & 1u)) >> 16);  // RNE
}
// pack two floats to packed bf16 pair (a -> low half)
DI uint32_t packbf2(float a, float b) {
    return __builtin_amdgcn_perm(__float_as_uint(b) + 0x8000u,
                                 __float_as_uint(a) + 0x8000u, 0x07060302u);
}

// ---------------------------------------------------------------------------
// Kernel 1: projections via MFMA (unchanged from r7-r9, ~11us).
//   th [blk][4096][32] bf16 (theta, pre-scaled by log2 e)
//   phT[blk][4096][32] bf16 (phi)
//   vP [blk][tile][o=32][k=64] bf16 (g, tile-blocked)
// ---------------------------------------------------------------------------
__global__ __launch_bounds__(256) void proj_kernel(
    const float* __restrict__ x,
    const float* __restrict__ tw, const float* __restrict__ tb,
    const float* __restrict__ pw, const float* __restrict__ pb,
    const float* __restrict__ gw, const float* __restrict__ gb,
    uint16_t* __restrict__ th, uint16_t* __restrict__ phT,
    uint16_t* __restrict__ vP)
{
    __shared__ uint16_t ldsg[32 * 68];
    int nt = blockIdx.x & 63, blk = blockIdx.x >> 6;
    int tid = threadIdx.x, wid = tid >> 6, lane = tid & 63;
    int quad = lane >> 4, low = lane & 15;

    int b = blk & 1, q = blk >> 1, qh = q >> 1, qw = q & 1;
    int pixA = wid * 16 + low;
    const float* xg = x + (size_t)b * 1048576 +
                      (size_t)(qh * 64 + nt) * 128 + qw * 64 + pixA;

    float a0[8], a1[8];
#pragma unroll
    for (int j = 0; j < 8; ++j) {
        a0[j] = xg[(size_t)(quad * 8 + j) * 16384];
        a1[j] = xg[(size_t)(32 + quad * 8 + j) * 16384];
    }
    union { uint32_t u[4]; bf16x8 v; } A0, A1;
#pragma unroll
    for (int j = 0; j < 4; ++j) {
        A0.u[j] = packbf2(a0[2*j], a0[2*j+1]);
        A1.u[j] = packbf2(a1[2*j], a1[2*j+1]);
    }

    auto dotile = [&](const float* W, const float* Bv, int o0) -> floatx4 {
        floatx4 acc;
        float bias = Bv[o0 + low];
#pragma unroll
        for (int r = 0; r < 4; ++r) acc[r] = bias;
        const float* wr = W + (o0 + low) * 64 + quad * 8;
        floatx4 w0a = *(const floatx4*)(wr);
        floatx4 w0b = *(const floatx4*)(wr + 4);
        floatx4 w1a = *(const floatx4*)(wr + 32);
        floatx4 w1b = *(const floatx4*)(wr + 36);
        union { uint32_t u[4]; bf16x8 v; } B0, B1;
        B0.u[0] = packbf2(w0a[0], w0a[1]); B0.u[1] = packbf2(w0a[2], w0a[3]);
        B0.u[2] = packbf2(w0b[0], w0b[1]); B0.u[3] = packbf2(w0b[2], w0b[3]);
        B1.u[0] = packbf2(w1a[0], w1a[1]); B1.u[1] = packbf2(w1a[2], w1a[3]);
        B1.u[2] = packbf2(w1b[0], w1b[1]); B1.u[3] = packbf2(w1b[2], w1b[3]);
        acc = __builtin_amdgcn_mfma_f32_16x16x32_bf16(A0.v, B0.v, acc, 0, 0, 0);
        acc = __builtin_amdgcn_mfma_f32_16x16x32_bf16(A1.v, B1.v, acc, 0, 0, 0);
        return acc;
    };

    size_t thbase = ((size_t)blk * 4096 + nt * 64 + wid * 16 + quad * 4) * 32;

    floatx4 t0 = dotile(tw, tb, 0), t1 = dotile(tw, tb, 16);
#pragma unroll
    for (int r = 0; r < 4; ++r) {
        th[thbase + r * 32 + low]      = f2bf(t0[r] * 1.44269504088896f);
        th[thbase + r * 32 + 16 + low] = f2bf(t1[r] * 1.44269504088896f);
    }
    floatx4 p0 = dotile(pw, pb, 0), p1 = dotile(pw, pb, 16);
#pragma unroll
    for (int r = 0; r < 4; ++r) {
        phT[thbase + r * 32 + low]      = f2bf(p0[r]);
        phT[thbase + r * 32 + 16 + low] = f2bf(p1[r]);
    }
    floatx4 g0 = dotile(gw, gb, 0), g1 = dotile(gw, gb, 16);
#pragma unroll
    for (int r = 0; r < 4; ++r) {
        ldsg[(low)      * 68 + wid * 16 + quad * 4 + r] = f2bf(g0[r]);
        ldsg[(16 + low) * 68 + wid * 16 + quad * 4 + r] = f2bf(g1[r]);
    }
    __syncthreads();
    {
        int o = tid >> 3, k = (tid & 7) * 8;
        const uint16_t* src = &ldsg[o * 68 + k];
        uint64_t lo = *(const uint64_t*)(src);
        uint64_t hi = *(const uint64_t*)(src + 4);
        union { uint64_t q[2]; u32x4 v; } outv;
        outv.q[0] = lo; outv.q[1] = hi;
        *(u32x4*)(vP + (size_t)blk * 131072 + nt * 2048 + tid * 8) = outv.v;
    }
}

// ---------------------------------------------------------------------------
// Kernel 2 (cooperative): flash attention + W-proj epilogue (wy stays in
// registers) + BN partials -> grid.sync() -> stats reduce + normalize +
// residual + direct output write. Eliminates wy round-trip (16MB) and the
// stats/final dispatches.
// grid: blk(8) x rg(64) = 512 WGs of 4 waves = exactly 2 WG/CU (coop-resident).
// ---------------------------------------------------------------------------
__global__ __launch_bounds__(256, 2) void mega_kernel(
    const uint16_t* __restrict__ th, const uint16_t* __restrict__ phT,
    const uint16_t* __restrict__ vP, const float* __restrict__ w_w,
    const float* __restrict__ w_b, const float* __restrict__ gamma,
    const float* __restrict__ beta, const float* __restrict__ x,
    float* __restrict__ out, float2* __restrict__ partials)
{
    __shared__ uint16_t ldsK[2][2][64 * 40];   // 20480 B
    __shared__ uint16_t ldsV[2][2][32 * 72];   // 18432 B
    __shared__ float sred[4][64][2];           // 2048 B
    __shared__ float sh2[2][4][64];            // 2048 B
    __shared__ float2 stl[64];                 // 512 B
    int rg  = blockIdx.x & 63;
    int blk = blockIdx.x >> 6;
    int tid = threadIdx.x, wid = tid >> 6, lane = tid & 63;
    int quad = lane >> 4, low = lane & 15;
    int n0 = rg * 64 + wid * 16;

    const uint16_t* thB = th  + (size_t)blk * 131072;
    const uint16_t* kG  = phT + (size_t)blk * 131072;
    const uint16_t* vG  = vP  + (size_t)blk * 131072;

    bf16x8 qf = *(const bf16x8*)(thB + (n0 + low) * 32 + quad * 8);

    const int kWr = (tid >> 2) * 40 + (tid & 3) * 8;
    const int vWr = (tid >> 3) * 72 + (tid & 7) * 8;
    const u32x4* kSrc = (const u32x4*)kG + tid;
    const u32x4* vSrc = (const u32x4*)vG + tid;

    u32x4 kr0 = kSrc[0],  kr1 = kSrc[256];
    u32x4 vr0 = vSrc[0],  vr1 = vSrc[256];
    *(u32x4*)(&ldsK[0][0][kWr]) = kr0;  *(u32x4*)(&ldsK[0][1][kWr]) = kr1;
    *(u32x4*)(&ldsV[0][0][vWr]) = vr0;  *(u32x4*)(&ldsV[0][1][vWr]) = vr1;
    __syncthreads();

    floatx4 zero = {0.f, 0.f, 0.f, 0.f};
    floatx4 oa0 = zero, oa1 = zero;
    float psum = 0.f;

    for (int t = 0; t < 32; ++t) {
        int buf = t & 1;
        if (t < 31) {
            kr0 = kSrc[(2*t + 2) * 256]; kr1 = kSrc[(2*t + 3) * 256];
            vr0 = vSrc[(2*t + 2) * 256]; vr1 = vSrc[(2*t + 3) * 256];
        }
#pragma unroll
        for (int s = 0; s < 2; ++s) {
            const uint16_t* Kb = ldsK[buf][s];
            const uint16_t* Vb = ldsV[buf][s];
            bf16x8  kf[4]; short4v va[4], vb[4];
#pragma unroll
            for (int c = 0; c < 4; ++c) {
                kf[c] = *(const bf16x8*)(Kb + (c * 16 + low) * 40 + quad * 8);
                va[c] = *(const short4v*)(Vb + low * 72 + c * 16 + quad * 4);
                vb[c] = *(const short4v*)(Vb + (16 + low) * 72 + c * 16 + quad * 4);
            }
            floatx4 sa[4];
#pragma unroll
            for (int c = 0; c < 4; ++c)
                sa[c] = __builtin_amdgcn_mfma_f32_16x16x32_bf16(kf[c], qf, zero, 0, 0, 0);
            union { uint32_t u[2]; short4v v; } P[4];
#pragma unroll
            for (int c = 0; c < 4; ++c) {
                float p0 = __builtin_amdgcn_exp2f(sa[c][0]);
                float p1 = __builtin_amdgcn_exp2f(sa[c][1]);
                float p2 = __builtin_amdgcn_exp2f(sa[c][2]);
                float p3 = __builtin_amdgcn_exp2f(sa[c][3]);
                psum += (p0 + p1) + (p2 + p3);
                P[c].u[0] = packbf2(p0, p1);
                P[c].u[1] = packbf2(p2, p3);
            }
#pragma unroll
            for (int c = 0; c < 4; ++c) {
                oa0 = __builtin_amdgcn_mfma_f32_16x16x16bf16_1k(va[c], P[c].v, oa0, 0, 0, 0);
                oa1 = __builtin_amdgcn_mfma_f32_16x16x16bf16_1k(vb[c], P[c].v, oa1, 0, 0, 0);
            }
        }
        if (t < 31) {
            *(u32x4*)(&ldsK[buf ^ 1][0][kWr]) = kr0;
            *(u32x4*)(&ldsK[buf ^ 1][1][kWr]) = kr1;
            *(u32x4*)(&ldsV[buf ^ 1][0][vWr]) = vr0;
            *(u32x4*)(&ldsV[buf ^ 1][1][vWr]) = vr1;
        }
        __syncthreads();
    }

    // psum: reduce over the 4 quads (each holds a 1024-key partial per query)
    psum += __shfl_xor(psum, 16);
    psum += __shfl_xor(psum, 32);
    float rinv = 1.0f / psum;

    union { uint32_t u[2]; short4v v; } Y0, Y1;
    Y0.u[0] = packbf2(oa0[0] * rinv, oa0[1] * rinv);
    Y0.u[1] = packbf2(oa0[2] * rinv, oa0[3] * rinv);
    Y1.u[0] = packbf2(oa1[0] * rinv, oa1[1] * rinv);
    Y1.u[1] = packbf2(oa1[2] * rinv, oa1[3] * rinv);

    // W-projection, wy kept in registers (acc[ct][r])
    floatx4 acc[4];
#pragma unroll
    for (int ct = 0; ct < 4; ++ct) {
        floatx4 a;
#pragma unroll
        for (int r = 0; r < 4; ++r) a[r] = w_b[ct * 16 + quad * 4 + r];
        floatx4 w0 = *(const floatx4*)(w_w + (ct * 16 + low) * 32 + quad * 4);
        floatx4 w1 = *(const floatx4*)(w_w + (ct * 16 + low) * 32 + 16 + quad * 4);
        union { uint32_t u[2]; short4v v; } W0, W1;
        W0.u[0] = packbf2(w0[0], w0[1]); W0.u[1] = packbf2(w0[2], w0[3]);
        W1.u[0] = packbf2(w1[0], w1[1]); W1.u[1] = packbf2(w1[2], w1[3]);
        a = __builtin_amdgcn_mfma_f32_16x16x16bf16_1k(W0.v, Y0.v, a, 0, 0, 0);
        a = __builtin_amdgcn_mfma_f32_16x16x16bf16_1k(W1.v, Y1.v, a, 0, 0, 0);
        acc[ct] = a;
#pragma unroll
        for (int r = 0; r < 4; ++r) {
            float s = a[r], ss = a[r] * a[r];
            s += __shfl_xor(s, 1); ss += __shfl_xor(ss, 1);
            s += __shfl_xor(s, 2); ss += __shfl_xor(ss, 2);
            s += __shfl_xor(s, 4); ss += __shfl_xor(ss, 4);
            s += __shfl_xor(s, 8); ss += __shfl_xor(ss, 8);
            if (low == 0) {
                sred[wid][ct * 16 + quad * 4 + r][0] = s;
                sred[wid][ct * 16 + quad * 4 + r][1] = ss;
            }
        }
    }
    __syncthreads();
    if (tid < 64) {
        float s  = sred[0][tid][0] + sred[1][tid][0] + sred[2][tid][0] + sred[3][tid][0];
        float ss = sred[0][tid][1] + sred[1][tid][1] + sred[2][tid][1] + sred[3][tid][1];
        partials[(size_t)blockIdx.x * 64 + tid] = make_float2(s, ss);
    }
    __threadfence();

    cg::this_grid().sync();

    // ---- phase B: BN stats (per-WG redundant reduce, L2-hot) ----
    int q = blk >> 1;
    {
        int c = tid & 63, g = tid >> 6;
        float S = 0.f, SS = 0.f;
        for (int w = g; w < 128; w += 4) {     // b(2) x rg(64)
            int wg = (q * 2 + (w >> 6)) * 64 + (w & 63);
            float2 p = partials[(size_t)wg * 64 + c];
            S += p.x; SS += p.y;
        }
        sh2[0][g][c] = S; sh2[1][g][c] = SS;
    }
    __syncthreads();
    if (tid < 64) {
        float St  = sh2[0][0][tid] + sh2[0][1][tid] + sh2[0][2][tid] + sh2[0][3][tid];
        float SSt = sh2[1][0][tid] + sh2[1][1][tid] + sh2[1][2][tid] + sh2[1][3][tid];
        float mu  = St * (1.0f / 8192.0f);
        float var = SSt * (1.0f / 8192.0f) - mu * mu;
        float scale = gamma[tid] * rsqrtf(var + 1e-5f);
        float shift = beta[tid] - mu * scale;
        stl[tid] = make_float2(scale, shift);
    }
    __syncthreads();

    // ---- normalize in-register wy + residual + direct output ----
    int b = blk & 1, qh = q >> 1, qw = q & 1;
    int n = n0 + low;
    int i = n >> 6, j = n & 63;
    size_t sp = (size_t)(qh * 64 + i) * 128 + qw * 64 + j;   // spatial offset
#pragma unroll
    for (int ct = 0; ct < 4; ++ct) {
#pragma unroll
        for (int r = 0; r < 4; ++r) {
            int ch = ct * 16 + quad * 4 + r;
            float2 sc = stl[ch];
            size_t xa = (size_t)(b * 64 + ch) * 16384 + sp;
            out[xa] = acc[ct][r] * sc.x + sc.y + x[xa];
        }
    }
}

// ---------------------------------------------------------------------------
extern "C" void kernel_launch(void* const* d_in, const int* in_sizes, int n_in,
                              void* d_out, int out_size, void* d_ws, size_t ws_size,
                              hipStream_t stream)
{
    const float* x       = (const float*)d_in[0];
    const float* g_w     = (const float*)d_in[1];
    const float* g_b     = (const float*)d_in[2];
    const float* theta_w = (const float*)d_in[3];
    const float* theta_b = (const float*)d_in[4];
    const float* phi_w   = (const float*)d_in[5];
    const float* phi_b   = (const float*)d_in[6];
    const float* w_w     = (const float*)d_in[7];
    const float* w_b     = (const float*)d_in[8];
    const float* gamma   = (const float*)d_in[9];
    const float* beta    = (const float*)d_in[10];

    char* ws = (char*)d_ws;
    uint16_t* th       = (uint16_t*)(ws);                 // 0 .. 2M
    uint16_t* phT      = (uint16_t*)(ws + (2u << 20));    // 2 .. 4M
    uint16_t* vP       = (uint16_t*)(ws + (4u << 20));    // 4 .. 6M
    float2*   partials = (float2*)(ws + (6u << 20));      // 256 KB
    float*    outp     = (float*)d_out;

    proj_kernel<<<512, 256, 0, stream>>>(x, theta_w, theta_b, phi_w, phi_b,
                                         g_w, g_b, th, phT, vP);

    void* args[] = { (void*)&th, (void*)&phT, (void*)&vP, (void*)&w_w,
                     (void*)&w_b, (void*)&gamma, (void*)&beta, (void*)&x,
                     (void*)&outp, (void*)&partials };
    hipLaunchCooperativeKernel((const void*)mega_kernel, dim3(512), dim3(256),
                               args, 0, stream);
}

// Round 11
// 204.802 us; speedup vs baseline: 1.1390x; 1.1390x over previous
//
#include <hip/hip_runtime.h>
#include <stdint.h>

typedef __bf16 bf16x8 __attribute__((ext_vector_type(8)));
typedef short  short4v __attribute__((ext_vector_type(4)));   // 4 x bf16 bits
typedef float  floatx4 __attribute__((ext_vector_type(4)));
typedef uint32_t u32x4 __attribute__((ext_vector_type(4)));

#define DI __device__ __forceinline__

DI uint16_t f2bf(float f) {
    union { float f; uint32_t i; } v; v.f = f;
    uint32_t u = v.i;
    return (uint16_t)((u + 0x7FFFu + ((u >> 16) & 1u)) >> 16);  // RNE
}
// pack two floats to packed bf16 pair (a -> low half)
DI uint32_t packbf2(float a, float b) {
    return __builtin_amdgcn_perm(__float_as_uint(b) + 0x8000u,
                                 __float_as_uint(a) + 0x8000u, 0x07060302u);
}

// ---------------------------------------------------------------------------
// Kernel 1: projections via MFMA (r7-r10, ~11us). Also zeroes the grid
// barrier counter used by mega_kernel (ws is poisoned 0xAA each launch).
//   th [blk][4096][32] bf16 (theta, pre-scaled by log2 e)
//   phT[blk][4096][32] bf16 (phi)
//   vP [blk][tile][o=32][k=64] bf16 (g, tile-blocked)
// ---------------------------------------------------------------------------
__global__ __launch_bounds__(256) void proj_kernel(
    const float* __restrict__ x,
    const float* __restrict__ tw, const float* __restrict__ tb,
    const float* __restrict__ pw, const float* __restrict__ pb,
    const float* __restrict__ gw, const float* __restrict__ gb,
    uint16_t* __restrict__ th, uint16_t* __restrict__ phT,
    uint16_t* __restrict__ vP, unsigned int* __restrict__ bar)
{
    __shared__ uint16_t ldsg[32 * 68];
    int nt = blockIdx.x & 63, blk = blockIdx.x >> 6;
    int tid = threadIdx.x, wid = tid >> 6, lane = tid & 63;
    int quad = lane >> 4, low = lane & 15;
    if (blockIdx.x == 0 && tid == 0) *bar = 0u;   // init grid barrier

    int b = blk & 1, q = blk >> 1, qh = q >> 1, qw = q & 1;
    int pixA = wid * 16 + low;
    const float* xg = x + (size_t)b * 1048576 +
                      (size_t)(qh * 64 + nt) * 128 + qw * 64 + pixA;

    float a0[8], a1[8];
#pragma unroll
    for (int j = 0; j < 8; ++j) {
        a0[j] = xg[(size_t)(quad * 8 + j) * 16384];
        a1[j] = xg[(size_t)(32 + quad * 8 + j) * 16384];
    }
    union { uint32_t u[4]; bf16x8 v; } A0, A1;
#pragma unroll
    for (int j = 0; j < 4; ++j) {
        A0.u[j] = packbf2(a0[2*j], a0[2*j+1]);
        A1.u[j] = packbf2(a1[2*j], a1[2*j+1]);
    }

    auto dotile = [&](const float* W, const float* Bv, int o0) -> floatx4 {
        floatx4 acc;
        float bias = Bv[o0 + low];
#pragma unroll
        for (int r = 0; r < 4; ++r) acc[r] = bias;
        const float* wr = W + (o0 + low) * 64 + quad * 8;
        floatx4 w0a = *(const floatx4*)(wr);
        floatx4 w0b = *(const floatx4*)(wr + 4);
        floatx4 w1a = *(const floatx4*)(wr + 32);
        floatx4 w1b = *(const floatx4*)(wr + 36);
        union { uint32_t u[4]; bf16x8 v; } B0, B1;
        B0.u[0] = packbf2(w0a[0], w0a[1]); B0.u[1] = packbf2(w0a[2], w0a[3]);
        B0.u[2] = packbf2(w0b[0], w0b[1]); B0.u[3] = packbf2(w0b[2], w0b[3]);
        B1.u[0] = packbf2(w1a[0], w1a[1]); B1.u[1] = packbf2(w1a[2], w1a[3]);
        B1.u[2] = packbf2(w1b[0], w1b[1]); B1.u[3] = packbf2(w1b[2], w1b[3]);
        acc = __builtin_amdgcn_mfma_f32_16x16x32_bf16(A0.v, B0.v, acc, 0, 0, 0);
        acc = __builtin_amdgcn_mfma_f32_16x16x32_bf16(A1.v, B1.v, acc, 0, 0, 0);
        return acc;
    };

    size_t thbase = ((size_t)blk * 4096 + nt * 64 + wid * 16 + quad * 4) * 32;

    floatx4 t0 = dotile(tw, tb, 0), t1 = dotile(tw, tb, 16);
#pragma unroll
    for (int r = 0; r < 4; ++r) {
        th[thbase + r * 32 + low]      = f2bf(t0[r] * 1.44269504088896f);
        th[thbase + r * 32 + 16 + low] = f2bf(t1[r] * 1.44269504088896f);
    }
    floatx4 p0 = dotile(pw, pb, 0), p1 = dotile(pw, pb, 16);
#pragma unroll
    for (int r = 0; r < 4; ++r) {
        phT[thbase + r * 32 + low]      = f2bf(p0[r]);
        phT[thbase + r * 32 + 16 + low] = f2bf(p1[r]);
    }
    floatx4 g0 = dotile(gw, gb, 0), g1 = dotile(gw, gb, 16);
#pragma unroll
    for (int r = 0; r < 4; ++r) {
        ldsg[(low)      * 68 + wid * 16 + quad * 4 + r] = f2bf(g0[r]);
        ldsg[(16 + low) * 68 + wid * 16 + quad * 4 + r] = f2bf(g1[r]);
    }
    __syncthreads();
    {
        int o = tid >> 3, k = (tid & 7) * 8;
        const uint16_t* src = &ldsg[o * 68 + k];
        uint64_t lo = *(const uint64_t*)(src);
        uint64_t hi = *(const uint64_t*)(src + 4);
        union { uint64_t q[2]; u32x4 v; } outv;
        outv.q[0] = lo; outv.q[1] = hi;
        *(u32x4*)(vP + (size_t)blk * 131072 + nt * 2048 + tid * 8) = outv.v;
    }
}

// ---------------------------------------------------------------------------
// Kernel 2: flash + W-proj (wy in registers) + BN partials -> MANUAL grid
// barrier (all 512 WGs co-resident: __launch_bounds__(256,2), 2 WG/CU by
// LDS 43.5KB and VGPR budget) -> stats reduce -> normalize+residual+store.
// Regular launch — r10 showed hipLaunchCooperativeKernel's dispatch path
// added ~80us of stall with identical pipe work.
// grid: blk(8) x rg(64) = 512 WGs of 4 waves.
// ---------------------------------------------------------------------------
__global__ __launch_bounds__(256, 2) void mega_kernel(
    const uint16_t* __restrict__ th, const uint16_t* __restrict__ phT,
    const uint16_t* __restrict__ vP, const float* __restrict__ w_w,
    const float* __restrict__ w_b, const float* __restrict__ gamma,
    const float* __restrict__ beta, const float* __restrict__ x,
    float* __restrict__ out, float2* __restrict__ partials,
    unsigned int* __restrict__ bar)
{
    __shared__ uint16_t ldsK[2][2][64 * 40];
    __shared__ uint16_t ldsV[2][2][32 * 72];
    __shared__ float sred[4][64][2];
    __shared__ float sh2[2][4][64];
    __shared__ float2 stl[64];
    int rg  = blockIdx.x & 63;
    int blk = blockIdx.x >> 6;
    int tid = threadIdx.x, wid = tid >> 6, lane = tid & 63;
    int quad = lane >> 4, low = lane & 15;
    int n0 = rg * 64 + wid * 16;

    const uint16_t* thB = th  + (size_t)blk * 131072;
    const uint16_t* kG  = phT + (size_t)blk * 131072;
    const uint16_t* vG  = vP  + (size_t)blk * 131072;

    bf16x8 qf = *(const bf16x8*)(thB + (n0 + low) * 32 + quad * 8);

    const int kWr = (tid >> 2) * 40 + (tid & 3) * 8;
    const int vWr = (tid >> 3) * 72 + (tid & 7) * 8;
    const u32x4* kSrc = (const u32x4*)kG + tid;
    const u32x4* vSrc = (const u32x4*)vG + tid;

    u32x4 kr0 = kSrc[0],  kr1 = kSrc[256];
    u32x4 vr0 = vSrc[0],  vr1 = vSrc[256];
    *(u32x4*)(&ldsK[0][0][kWr]) = kr0;  *(u32x4*)(&ldsK[0][1][kWr]) = kr1;
    *(u32x4*)(&ldsV[0][0][vWr]) = vr0;  *(u32x4*)(&ldsV[0][1][vWr]) = vr1;
    __syncthreads();

    floatx4 zero = {0.f, 0.f, 0.f, 0.f};
    floatx4 oa0 = zero, oa1 = zero, os = zero;
    union { uint32_t u[2]; short4v v; } ones;
    ones.u[0] = 0x3F803F80u; ones.u[1] = 0x3F803F80u;

    for (int t = 0; t < 32; ++t) {
        int buf = t & 1;
        if (t < 31) {
            kr0 = kSrc[(2*t + 2) * 256]; kr1 = kSrc[(2*t + 3) * 256];
            vr0 = vSrc[(2*t + 2) * 256]; vr1 = vSrc[(2*t + 3) * 256];
        }
#pragma unroll
        for (int s = 0; s < 2; ++s) {
            const uint16_t* Kb = ldsK[buf][s];
            const uint16_t* Vb = ldsV[buf][s];
            bf16x8  kf[4]; short4v va[4], vb[4];
#pragma unroll
            for (int c = 0; c < 4; ++c) {
                kf[c] = *(const bf16x8*)(Kb + (c * 16 + low) * 40 + quad * 8);
                va[c] = *(const short4v*)(Vb + low * 72 + c * 16 + quad * 4);
                vb[c] = *(const short4v*)(Vb + (16 + low) * 72 + c * 16 + quad * 4);
            }
            floatx4 sa[4];
#pragma unroll
            for (int c = 0; c < 4; ++c)
                sa[c] = __builtin_amdgcn_mfma_f32_16x16x32_bf16(kf[c], qf, zero, 0, 0, 0);
            union { uint32_t u[2]; short4v v; } P[4];
#pragma unroll
            for (int c = 0; c < 4; ++c) {
                float p0 = __builtin_amdgcn_exp2f(sa[c][0]);
                float p1 = __builtin_amdgcn_exp2f(sa[c][1]);
                float p2 = __builtin_amdgcn_exp2f(sa[c][2]);
                float p3 = __builtin_amdgcn_exp2f(sa[c][3]);
                P[c].u[0] = packbf2(p0, p1);
                P[c].u[1] = packbf2(p2, p3);
            }
#pragma unroll
            for (int c = 0; c < 4; ++c) {
                oa0 = __builtin_amdgcn_mfma_f32_16x16x16bf16_1k(va[c], P[c].v, oa0, 0, 0, 0);
                oa1 = __builtin_amdgcn_mfma_f32_16x16x16bf16_1k(vb[c], P[c].v, oa1, 0, 0, 0);
                os  = __builtin_amdgcn_mfma_f32_16x16x16bf16_1k(ones.v, P[c].v, os, 0, 0, 0);
            }
        }
        if (t < 31) {
            *(u32x4*)(&ldsK[buf ^ 1][0][kWr]) = kr0;
            *(u32x4*)(&ldsK[buf ^ 1][1][kWr]) = kr1;
            *(u32x4*)(&ldsV[buf ^ 1][0][vWr]) = vr0;
            *(u32x4*)(&ldsV[buf ^ 1][1][vWr]) = vr1;
        }
        __syncthreads();
    }

    float rinv = 1.0f / os[0];
    union { uint32_t u[2]; short4v v; } Y0, Y1;
    Y0.u[0] = packbf2(oa0[0] * rinv, oa0[1] * rinv);
    Y0.u[1] = packbf2(oa0[2] * rinv, oa0[3] * rinv);
    Y1.u[0] = packbf2(oa1[0] * rinv, oa1[1] * rinv);
    Y1.u[1] = packbf2(oa1[2] * rinv, oa1[3] * rinv);

    // W-projection, wy kept in registers acc[4]
    floatx4 acc[4];
#pragma unroll
    for (int ct = 0; ct < 4; ++ct) {
        floatx4 a;
#pragma unroll
        for (int r = 0; r < 4; ++r) a[r] = w_b[ct * 16 + quad * 4 + r];
        floatx4 w0 = *(const floatx4*)(w_w + (ct * 16 + low) * 32 + quad * 4);
        floatx4 w1 = *(const floatx4*)(w_w + (ct * 16 + low) * 32 + 16 + quad * 4);
        union { uint32_t u[2]; short4v v; } W0, W1;
        W0.u[0] = packbf2(w0[0], w0[1]); W0.u[1] = packbf2(w0[2], w0[3]);
        W1.u[0] = packbf2(w1[0], w1[1]); W1.u[1] = packbf2(w1[2], w1[3]);
        a = __builtin_amdgcn_mfma_f32_16x16x16bf16_1k(W0.v, Y0.v, a, 0, 0, 0);
        a = __builtin_amdgcn_mfma_f32_16x16x16bf16_1k(W1.v, Y1.v, a, 0, 0, 0);
        acc[ct] = a;
#pragma unroll
        for (int r = 0; r < 4; ++r) {
            float s = a[r], ss = a[r] * a[r];
            s += __shfl_xor(s, 1); ss += __shfl_xor(ss, 1);
            s += __shfl_xor(s, 2); ss += __shfl_xor(ss, 2);
            s += __shfl_xor(s, 4); ss += __shfl_xor(ss, 4);
            s += __shfl_xor(s, 8); ss += __shfl_xor(ss, 8);
            if (low == 0) {
                sred[wid][ct * 16 + quad * 4 + r][0] = s;
                sred[wid][ct * 16 + quad * 4 + r][1] = ss;
            }
        }
    }
    __syncthreads();
    if (tid < 64) {
        float s  = sred[0][tid][0] + sred[1][tid][0] + sred[2][tid][0] + sred[3][tid][0];
        float ss = sred[0][tid][1] + sred[1][tid][1] + sred[2][tid][1] + sred[3][tid][1];
        partials[(size_t)blockIdx.x * 64 + tid] = make_float2(s, ss);
    }
    __syncthreads();

    // ---- manual grid barrier (all 512 WGs co-resident at 2 WG/CU) ----
    if (tid == 0) {
        __threadfence();   // release partials
        __hip_atomic_fetch_add(bar, 1u, __ATOMIC_ACQ_REL, __HIP_MEMORY_SCOPE_AGENT);
        while (__hip_atomic_load(bar, __ATOMIC_ACQUIRE, __HIP_MEMORY_SCOPE_AGENT) < 512u)
            __builtin_amdgcn_s_sleep(2);
        __threadfence();   // acquire
    }
    __syncthreads();

    // ---- phase B: BN stats (per-WG redundant reduce, L2/L3-hot) ----
    int q = blk >> 1;
    {
        int c = tid & 63, g = tid >> 6;
        float S = 0.f, SS = 0.f;
        for (int w = g; w < 128; w += 4) {     // b(2) x rg(64)
            int wg = (q * 2 + (w >> 6)) * 64 + (w & 63);
            float2 p = partials[(size_t)wg * 64 + c];
            S += p.x; SS += p.y;
        }
        sh2[0][g][c] = S; sh2[1][g][c] = SS;
    }
    __syncthreads();
    if (tid < 64) {
        float St  = sh2[0][0][tid] + sh2[0][1][tid] + sh2[0][2][tid] + sh2[0][3][tid];
        float SSt = sh2[1][0][tid] + sh2[1][1][tid] + sh2[1][2][tid] + sh2[1][3][tid];
        float mu  = St * (1.0f / 8192.0f);
        float var = SSt * (1.0f / 8192.0f) - mu * mu;
        float scale = gamma[tid] * rsqrtf(var + 1e-5f);
        float shift = beta[tid] - mu * scale;
        stl[tid] = make_float2(scale, shift);
    }
    __syncthreads();

    // ---- phase C: normalize in-register wy + residual + direct output ----
    int b = blk & 1, qh = q >> 1, qw = q & 1;
    int n = n0 + low;
    int i = n >> 6, j = n & 63;
    size_t sp = (size_t)(qh * 64 + i) * 128 + qw * 64 + j;
#pragma unroll
    for (int ct = 0; ct < 4; ++ct) {
#pragma unroll
        for (int r = 0; r < 4; ++r) {
            int ch = ct * 16 + quad * 4 + r;
            float2 sc = stl[ch];
            size_t xa = (size_t)(b * 64 + ch) * 16384 + sp;
            out[xa] = acc[ct][r] * sc.x + sc.y + x[xa];
        }
    }
}

// ---------------------------------------------------------------------------
extern "C" void kernel_launch(void* const* d_in, const int* in_sizes, int n_in,
                              void* d_out, int out_size, void* d_ws, size_t ws_size,
                              hipStream_t stream)
{
    const float* x       = (const float*)d_in[0];
    const float* g_w     = (const float*)d_in[1];
    const float* g_b     = (const float*)d_in[2];
    const float* theta_w = (const float*)d_in[3];
    const float* theta_b = (const float*)d_in[4];
    const float* phi_w   = (const float*)d_in[5];
    const float* phi_b   = (const float*)d_in[6];
    const float* w_w     = (const float*)d_in[7];
    const float* w_b     = (const float*)d_in[8];
    const float* gamma   = (const float*)d_in[9];
    const float* beta    = (const float*)d_in[10];

    char* ws = (char*)d_ws;
    uint16_t* th       = (uint16_t*)(ws);                 // 0 .. 2M
    uint16_t* phT      = (uint16_t*)(ws + (2u << 20));    // 2 .. 4M
    uint16_t* vP       = (uint16_t*)(ws + (4u << 20));    // 4 .. 6M
    float2*   partials = (float2*)(ws + (6u << 20));      // 256 KB
    unsigned int* bar  = (unsigned int*)(ws + (6u << 20) + (1u << 18));

    proj_kernel<<<512, 256, 0, stream>>>(x, theta_w, theta_b, phi_w, phi_b,
                                         g_w, g_b, th, phT, vP, bar);
    mega_kernel<<<512, 256, 0, stream>>>(th, phT, vP, w_w, w_b, gamma, beta,
                                         x, (float*)d_out, partials, bar);
}

// Round 12
// 149.939 us; speedup vs baseline: 1.5558x; 1.3659x over previous
//
#include <hip/hip_runtime.h>
#include <stdint.h>

typedef __bf16 bf16x8 __attribute__((ext_vector_type(8)));
typedef short  short4v __attribute__((ext_vector_type(4)));   // 4 x bf16 bits
typedef float  floatx4 __attribute__((ext_vector_type(4)));
typedef uint32_t u32x4 __attribute__((ext_vector_type(4)));

#define DI __device__ __forceinline__

DI uint16_t f2bf(float f) {
    union { float f; uint32_t i; } v; v.f = f;
    uint32_t u = v.i;
    return (uint16_t)((u + 0x7FFFu + ((u >> 16) & 1u)) >> 16);  // RNE
}
// pack two floats to packed bf16 pair (a -> low half)
DI uint32_t packbf2(float a, float b) {
    return __builtin_amdgcn_perm(__float_as_uint(b) + 0x8000u,
                                 __float_as_uint(a) + 0x8000u, 0x07060302u);
}

// ---------------------------------------------------------------------------
// Kernel 1: projections via MFMA (r7 exact, ~10us).
//   th [blk][4096][32] bf16 (theta, pre-scaled by log2 e)
//   phT[blk][4096][32] bf16 (phi)
//   vP [blk][tile][o=32][k=64] bf16 (g, tile-blocked)
// ---------------------------------------------------------------------------
__global__ __launch_bounds__(256) void proj_kernel(
    const float* __restrict__ x,
    const float* __restrict__ tw, const float* __restrict__ tb,
    const float* __restrict__ pw, const float* __restrict__ pb,
    const float* __restrict__ gw, const float* __restrict__ gb,
    uint16_t* __restrict__ th, uint16_t* __restrict__ phT,
    uint16_t* __restrict__ vP)
{
    __shared__ uint16_t ldsg[32 * 68];
    int nt = blockIdx.x & 63, blk = blockIdx.x >> 6;
    int tid = threadIdx.x, wid = tid >> 6, lane = tid & 63;
    int quad = lane >> 4, low = lane & 15;

    int b = blk & 1, q = blk >> 1, qh = q >> 1, qw = q & 1;
    int pixA = wid * 16 + low;
    const float* xg = x + (size_t)b * 1048576 +
                      (size_t)(qh * 64 + nt) * 128 + qw * 64 + pixA;

    float a0[8], a1[8];
#pragma unroll
    for (int j = 0; j < 8; ++j) {
        a0[j] = xg[(size_t)(quad * 8 + j) * 16384];
        a1[j] = xg[(size_t)(32 + quad * 8 + j) * 16384];
    }
    union { uint32_t u[4]; bf16x8 v; } A0, A1;
#pragma unroll
    for (int j = 0; j < 4; ++j) {
        A0.u[j] = packbf2(a0[2*j], a0[2*j+1]);
        A1.u[j] = packbf2(a1[2*j], a1[2*j+1]);
    }

    auto dotile = [&](const float* W, const float* Bv, int o0) -> floatx4 {
        floatx4 acc;
        float bias = Bv[o0 + low];
#pragma unroll
        for (int r = 0; r < 4; ++r) acc[r] = bias;
        const float* wr = W + (o0 + low) * 64 + quad * 8;
        floatx4 w0a = *(const floatx4*)(wr);
        floatx4 w0b = *(const floatx4*)(wr + 4);
        floatx4 w1a = *(const floatx4*)(wr + 32);
        floatx4 w1b = *(const floatx4*)(wr + 36);
        union { uint32_t u[4]; bf16x8 v; } B0, B1;
        B0.u[0] = packbf2(w0a[0], w0a[1]); B0.u[1] = packbf2(w0a[2], w0a[3]);
        B0.u[2] = packbf2(w0b[0], w0b[1]); B0.u[3] = packbf2(w0b[2], w0b[3]);
        B1.u[0] = packbf2(w1a[0], w1a[1]); B1.u[1] = packbf2(w1a[2], w1a[3]);
        B1.u[2] = packbf2(w1b[0], w1b[1]); B1.u[3] = packbf2(w1b[2], w1b[3]);
        acc = __builtin_amdgcn_mfma_f32_16x16x32_bf16(A0.v, B0.v, acc, 0, 0, 0);
        acc = __builtin_amdgcn_mfma_f32_16x16x32_bf16(A1.v, B1.v, acc, 0, 0, 0);
        return acc;
    };

    size_t thbase = ((size_t)blk * 4096 + nt * 64 + wid * 16 + quad * 4) * 32;

    floatx4 t0 = dotile(tw, tb, 0), t1 = dotile(tw, tb, 16);
#pragma unroll
    for (int r = 0; r < 4; ++r) {
        th[thbase + r * 32 + low]      = f2bf(t0[r] * 1.44269504088896f);
        th[thbase + r * 32 + 16 + low] = f2bf(t1[r] * 1.44269504088896f);
    }
    floatx4 p0 = dotile(pw, pb, 0), p1 = dotile(pw, pb, 16);
#pragma unroll
    for (int r = 0; r < 4; ++r) {
        phT[thbase + r * 32 + low]      = f2bf(p0[r]);
        phT[thbase + r * 32 + 16 + low] = f2bf(p1[r]);
    }
    floatx4 g0 = dotile(gw, gb, 0), g1 = dotile(gw, gb, 16);
#pragma unroll
    for (int r = 0; r < 4; ++r) {
        ldsg[(low)      * 68 + wid * 16 + quad * 4 + r] = f2bf(g0[r]);
        ldsg[(16 + low) * 68 + wid * 16 + quad * 4 + r] = f2bf(g1[r]);
    }
    __syncthreads();
    {
        int o = tid >> 3, k = (tid & 7) * 8;
        const uint16_t* src = &ldsg[o * 68 + k];
        uint64_t lo = *(const uint64_t*)(src);
        uint64_t hi = *(const uint64_t*)(src + 4);
        union { uint64_t q[2]; u32x4 v; } outv;
        outv.q[0] = lo; outv.q[1] = hi;
        *(u32x4*)(vP + (size_t)blk * 131072 + nt * 2048 + tid * 8) = outv.v;
    }
}

// ---------------------------------------------------------------------------
// Kernel 2: flash + fused W-epilogue (r7 structure) with r8's 2-Q-frag ILP.
// WG = 128 threads (2 waves x 32 q-rows = 64 rows), grid 512 -> 4 WG/CU
// (LDS 39.9KB). Both Q-frags share every K/V LDS read; full K sweep.
// grid: blk(8) x rg(64) = 512 WGs.
// ---------------------------------------------------------------------------
__global__ __launch_bounds__(128, 2) void flash_kernel(
    const uint16_t* __restrict__ th, const uint16_t* __restrict__ phT,
    const uint16_t* __restrict__ vP, const float* __restrict__ w_w,
    const float* __restrict__ w_b, float* __restrict__ wy,
    float2* __restrict__ partials)
{
    __shared__ uint16_t ldsK[2][2][64 * 40];   // 20480 B
    __shared__ uint16_t ldsV[2][2][32 * 72];   // 18432 B
    __shared__ float sred[2][64][2];           // 1024 B
    int rg  = blockIdx.x & 63;
    int blk = blockIdx.x >> 6;
    int tid = threadIdx.x, wid = tid >> 6, lane = tid & 63;
    int quad = lane >> 4, low = lane & 15;
    int n0 = rg * 64 + wid * 32;               // wave owns rows n0..n0+31

    const uint16_t* thB = th  + (size_t)blk * 131072;
    const uint16_t* kG  = phT + (size_t)blk * 131072;
    const uint16_t* vG  = vP  + (size_t)blk * 131072;

    bf16x8 qf0 = *(const bf16x8*)(thB + (n0 + low) * 32 + quad * 8);
    bf16x8 qf1 = *(const bf16x8*)(thB + (n0 + 16 + low) * 32 + quad * 8);

    // staging: 128 threads, 2 x 16B per subtile each for K and V
    const int kWr = (tid >> 2) * 40 + (tid & 3) * 8;      // + second half +1280
    const int vWr = (tid >> 3) * 72 + (tid & 7) * 8;      // + second half +1152
    const u32x4* kSrc = (const u32x4*)kG + tid;           // subtile s: +s*256
    const u32x4* vSrc = (const u32x4*)vG + tid;

    u32x4 kr[4], vr[4];
#pragma unroll
    for (int s = 0; s < 2; ++s) {
        kr[2*s]   = kSrc[s * 256];       kr[2*s+1] = kSrc[s * 256 + 128];
        vr[2*s]   = vSrc[s * 256];       vr[2*s+1] = vSrc[s * 256 + 128];
    }
#pragma unroll
    for (int s = 0; s < 2; ++s) {
        *(u32x4*)(&ldsK[0][s][kWr])        = kr[2*s];
        *(u32x4*)(&ldsK[0][s][kWr + 1280]) = kr[2*s+1];
        *(u32x4*)(&ldsV[0][s][vWr])        = vr[2*s];
        *(u32x4*)(&ldsV[0][s][vWr + 1152]) = vr[2*s+1];
    }
    __syncthreads();

    floatx4 zero = {0.f, 0.f, 0.f, 0.f};
    floatx4 oa00 = zero, oa01 = zero, oa10 = zero, oa11 = zero;
    floatx4 os0 = zero, os1 = zero;
    union { uint32_t u[2]; short4v v; } ones;
    ones.u[0] = 0x3F803F80u; ones.u[1] = 0x3F803F80u;

    for (int t = 0; t < 32; ++t) {
        int buf = t & 1;
        if (t < 31) {
#pragma unroll
            for (int s = 0; s < 2; ++s) {
                kr[2*s]   = kSrc[(2*t + 2 + s) * 256];
                kr[2*s+1] = kSrc[(2*t + 2 + s) * 256 + 128];
                vr[2*s]   = vSrc[(2*t + 2 + s) * 256];
                vr[2*s+1] = vSrc[(2*t + 2 + s) * 256 + 128];
            }
        }
#pragma unroll
        for (int s = 0; s < 2; ++s) {
            const uint16_t* Kb = ldsK[buf][s];
            const uint16_t* Vb = ldsV[buf][s];
            bf16x8  kf[4]; short4v va[4], vb[4];
#pragma unroll
            for (int c = 0; c < 4; ++c) {
                kf[c] = *(const bf16x8*)(Kb + (c * 16 + low) * 40 + quad * 8);
                va[c] = *(const short4v*)(Vb + low * 72 + c * 16 + quad * 4);
                vb[c] = *(const short4v*)(Vb + (16 + low) * 72 + c * 16 + quad * 4);
            }
            floatx4 sa0[4], sa1[4];
#pragma unroll
            for (int c = 0; c < 4; ++c) {
                sa0[c] = __builtin_amdgcn_mfma_f32_16x16x32_bf16(kf[c], qf0, zero, 0, 0, 0);
                sa1[c] = __builtin_amdgcn_mfma_f32_16x16x32_bf16(kf[c], qf1, zero, 0, 0, 0);
            }
            union { uint32_t u[2]; short4v v; } P0[4], P1[4];
#pragma unroll
            for (int c = 0; c < 4; ++c) {
                float p0 = __builtin_amdgcn_exp2f(sa0[c][0]);
                float p1 = __builtin_amdgcn_exp2f(sa0[c][1]);
                float p2 = __builtin_amdgcn_exp2f(sa0[c][2]);
                float p3 = __builtin_amdgcn_exp2f(sa0[c][3]);
                P0[c].u[0] = packbf2(p0, p1);
                P0[c].u[1] = packbf2(p2, p3);
                float r0 = __builtin_amdgcn_exp2f(sa1[c][0]);
                float r1 = __builtin_amdgcn_exp2f(sa1[c][1]);
                float r2 = __builtin_amdgcn_exp2f(sa1[c][2]);
                float r3 = __builtin_amdgcn_exp2f(sa1[c][3]);
                P1[c].u[0] = packbf2(r0, r1);
                P1[c].u[1] = packbf2(r2, r3);
            }
#pragma unroll
            for (int c = 0; c < 4; ++c) {
                oa00 = __builtin_amdgcn_mfma_f32_16x16x16bf16_1k(va[c], P0[c].v, oa00, 0, 0, 0);
                oa01 = __builtin_amdgcn_mfma_f32_16x16x16bf16_1k(vb[c], P0[c].v, oa01, 0, 0, 0);
                os0  = __builtin_amdgcn_mfma_f32_16x16x16bf16_1k(ones.v, P0[c].v, os0, 0, 0, 0);
                oa10 = __builtin_amdgcn_mfma_f32_16x16x16bf16_1k(va[c], P1[c].v, oa10, 0, 0, 0);
                oa11 = __builtin_amdgcn_mfma_f32_16x16x16bf16_1k(vb[c], P1[c].v, oa11, 0, 0, 0);
                os1  = __builtin_amdgcn_mfma_f32_16x16x16bf16_1k(ones.v, P1[c].v, os1, 0, 0, 0);
            }
        }
        if (t < 31) {
#pragma unroll
            for (int s = 0; s < 2; ++s) {
                *(u32x4*)(&ldsK[buf ^ 1][s][kWr])        = kr[2*s];
                *(u32x4*)(&ldsK[buf ^ 1][s][kWr + 1280]) = kr[2*s+1];
                *(u32x4*)(&ldsV[buf ^ 1][s][vWr])        = vr[2*s];
                *(u32x4*)(&ldsV[buf ^ 1][s][vWr + 1152]) = vr[2*s+1];
            }
        }
        __syncthreads();
    }

    // ---- epilogue: normalize, W-projection via MFMA, BN partials ----
    float rinv0 = 1.0f / os0[0];
    float rinv1 = 1.0f / os1[0];
    union { uint32_t u[2]; short4v v; } Y00, Y01, Y10, Y11;
    Y00.u[0] = packbf2(oa00[0] * rinv0, oa00[1] * rinv0);
    Y00.u[1] = packbf2(oa00[2] * rinv0, oa00[3] * rinv0);
    Y01.u[0] = packbf2(oa01[0] * rinv0, oa01[1] * rinv0);
    Y01.u[1] = packbf2(oa01[2] * rinv0, oa01[3] * rinv0);
    Y10.u[0] = packbf2(oa10[0] * rinv1, oa10[1] * rinv1);
    Y10.u[1] = packbf2(oa10[2] * rinv1, oa10[3] * rinv1);
    Y11.u[0] = packbf2(oa11[0] * rinv1, oa11[1] * rinv1);
    Y11.u[1] = packbf2(oa11[2] * rinv1, oa11[3] * rinv1);

    float* wyB = wy + (size_t)blk * 262144;
    int n = n0 + low;
#pragma unroll
    for (int ct = 0; ct < 4; ++ct) {
        floatx4 a0, a1;
        float bias0 = w_b[ct * 16 + quad * 4];
        float bias1 = w_b[ct * 16 + quad * 4 + 1];
        float bias2 = w_b[ct * 16 + quad * 4 + 2];
        float bias3 = w_b[ct * 16 + quad * 4 + 3];
        a0[0] = bias0; a0[1] = bias1; a0[2] = bias2; a0[3] = bias3;
        a1 = a0;
        floatx4 w0 = *(const floatx4*)(w_w + (ct * 16 + low) * 32 + quad * 4);
        floatx4 w1 = *(const floatx4*)(w_w + (ct * 16 + low) * 32 + 16 + quad * 4);
        union { uint32_t u[2]; short4v v; } W0, W1;
        W0.u[0] = packbf2(w0[0], w0[1]); W0.u[1] = packbf2(w0[2], w0[3]);
        W1.u[0] = packbf2(w1[0], w1[1]); W1.u[1] = packbf2(w1[2], w1[3]);
        a0 = __builtin_amdgcn_mfma_f32_16x16x16bf16_1k(W0.v, Y00.v, a0, 0, 0, 0);
        a0 = __builtin_amdgcn_mfma_f32_16x16x16bf16_1k(W1.v, Y01.v, a0, 0, 0, 0);
        a1 = __builtin_amdgcn_mfma_f32_16x16x16bf16_1k(W0.v, Y10.v, a1, 0, 0, 0);
        a1 = __builtin_amdgcn_mfma_f32_16x16x16bf16_1k(W1.v, Y11.v, a1, 0, 0, 0);
#pragma unroll
        for (int r = 0; r < 4; ++r) {
            int ch = ct * 16 + quad * 4 + r;
            wyB[(size_t)ch * 4096 + n]      = a0[r];
            wyB[(size_t)ch * 4096 + n + 16] = a1[r];
            float s = a0[r] + a1[r];
            float ss = a0[r] * a0[r] + a1[r] * a1[r];
            s += __shfl_xor(s, 1); ss += __shfl_xor(ss, 1);
            s += __shfl_xor(s, 2); ss += __shfl_xor(ss, 2);
            s += __shfl_xor(s, 4); ss += __shfl_xor(ss, 4);
            s += __shfl_xor(s, 8); ss += __shfl_xor(ss, 8);
            if (low == 0) {
                sred[wid][ch][0] = s;
                sred[wid][ch][1] = ss;
            }
        }
    }
    __syncthreads();
    if (tid < 64) {
        float s  = sred[0][tid][0] + sred[1][tid][0];
        float ss = sred[0][tid][1] + sred[1][tid][1];
        partials[(size_t)blockIdx.x * 64 + tid] = make_float2(s, ss);
    }
}

// ---------------------------------------------------------------------------
// Kernel 3: BN stats — grid 4 (q), block 256 (=4 groups x 64 c).
// ---------------------------------------------------------------------------
__global__ __launch_bounds__(256) void stats_kernel(
    const float2* __restrict__ partials, const float* __restrict__ gamma,
    const float* __restrict__ beta, float2* __restrict__ stats)
{
    int q = blockIdx.x;
    int c = threadIdx.x & 63, g = threadIdx.x >> 6;
    float S = 0.f, SS = 0.f;
    for (int w = g; w < 128; w += 4) {         // b(2) x rg(64)
        int wg = (q * 2 + (w >> 6)) * 64 + (w & 63);
        float2 p = partials[(size_t)wg * 64 + c];
        S += p.x; SS += p.y;
    }
    __shared__ float sh[2][4][64];
    sh[0][g][c] = S; sh[1][g][c] = SS;
    __syncthreads();
    if (threadIdx.x < 64) {
        int cc = threadIdx.x;
        float St  = sh[0][0][cc] + sh[0][1][cc] + sh[0][2][cc] + sh[0][3][cc];
        float SSt = sh[1][0][cc] + sh[1][1][cc] + sh[1][2][cc] + sh[1][3][cc];
        float mu  = St * (1.0f / 8192.0f);
        float var = SSt * (1.0f / 8192.0f) - mu * mu;
        float scale = gamma[cc] * rsqrtf(var + 1e-5f);
        float shift = beta[cc] - mu * scale;
        stats[q * 64 + cc] = make_float2(scale, shift);
    }
}

// ---------------------------------------------------------------------------
// Kernel 4: out = (wy * scale + shift) + x, float4-vectorized reassembly.
// ---------------------------------------------------------------------------
__global__ __launch_bounds__(256) void final_kernel(
    const float* __restrict__ wy, const float2* __restrict__ stats,
    const float* __restrict__ x, float* __restrict__ out)
{
    size_t base = ((size_t)blockIdx.x * 256 + threadIdx.x) * 4;
    int n   = (int)(base & 4095);
    int c   = (int)((base >> 12) & 63);
    int blk = (int)(base >> 18);
    int b = blk & 1, q = blk >> 1, qh = q >> 1, qw = q & 1;
    int i = n >> 6, j = n & 63;
    float2 sc = stats[q * 64 + c];
    floatx4 wv = *(const floatx4*)(wy + base);
    size_t xa = ((size_t)(b * 64 + c) * 128 + (qh * 64 + i)) * 128 + qw * 64 + j;
    floatx4 xv = *(const floatx4*)(x + xa);
    floatx4 ov;
#pragma unroll
    for (int k = 0; k < 4; ++k) ov[k] = wv[k] * sc.x + sc.y + xv[k];
    *(floatx4*)(out + xa) = ov;
}

// ---------------------------------------------------------------------------
extern "C" void kernel_launch(void* const* d_in, const int* in_sizes, int n_in,
                              void* d_out, int out_size, void* d_ws, size_t ws_size,
                              hipStream_t stream)
{
    const float* x       = (const float*)d_in[0];
    const float* g_w     = (const float*)d_in[1];
    const float* g_b     = (const float*)d_in[2];
    const float* theta_w = (const float*)d_in[3];
    const float* theta_b = (const float*)d_in[4];
    const float* phi_w   = (const float*)d_in[5];
    const float* phi_b   = (const float*)d_in[6];
    const float* w_w     = (const float*)d_in[7];
    const float* w_b     = (const float*)d_in[8];
    const float* gamma   = (const float*)d_in[9];
    const float* beta    = (const float*)d_in[10];

    char* ws = (char*)d_ws;
    uint16_t* th       = (uint16_t*)(ws);                 // 0 .. 2M
    uint16_t* phT      = (uint16_t*)(ws + (2u << 20));    // 2 .. 4M
    uint16_t* vP       = (uint16_t*)(ws + (4u << 20));    // 4 .. 6M
    float*    wy       = (float*)(ws + (6u << 20));       // 6 .. 14M
    float2*   partials = (float2*)(ws + (14u << 20));     // 256 KB
    float2*   stats    = (float2*)(ws + (14u << 20) + (1u << 18));

    proj_kernel  <<<512,  256, 0, stream>>>(x, theta_w, theta_b, phi_w, phi_b,
                                            g_w, g_b, th, phT, vP);
    flash_kernel <<<512,  128, 0, stream>>>(th, phT, vP, w_w, w_b, wy, partials);
    stats_kernel <<<4,    256, 0, stream>>>(partials, gamma, beta, stats);
    final_kernel <<<2048, 256, 0, stream>>>(wy, stats, x, (float*)d_out);
}